// Round 2
// baseline (148.785 us; speedup 1.0000x reference)
//
#include <hip/hip_runtime.h>
#include <hip/hip_bf16.h>
#include <stdint.h>

// SketchConv2d: out = conv2d(x, Weff) + bias, where
// Weff[o,f] = (1/4) * sum_{n,s} sketches[n,f,s] * signed[n,s,o]
// f channel-major flat (c*9 + kh*3 + kw), matching unfold/patches ordering.
//
// B=32, CIN=128, H=W=64, OUT=256, KH=KW=3, H2=W2=62, NSK=4, SDIM=128.
//
// Structure (round 2): barrier-free K-loop.
//  - kernel 1 writes Weff bf16 FRAGMENT-ORDERED into ws:
//      [step s(18)][o16(16)][ks(2)][lane(64)][8 bf16]  (1 KB per fragment)
//    so conv waves load A fragments coalesced, straight to registers.
//  - conv block = (b, i): 256 o x 64 j. B = x[b,:,i..i+2,:] staged ONCE
//    into LDS as bf16 [3][64 j][128 c], XOR-swizzled. 18 K-steps read B
//    frags from LDS + A frags from regs (1-step register double-buffer).

#define BATCH 32
#define CIN   128
#define HH    64
#define WW    64
#define OUTC  256
#define H2    62
#define W2    62
#define NSTEP 18
#define A_TILE_BYTES 32768            // 16 o16 * 2 ks * 1024
#define WS_A_BYTES (NSTEP * A_TILE_BYTES)

typedef __bf16 bf16x8 __attribute__((ext_vector_type(8)));
typedef float  f32x4  __attribute__((ext_vector_type(4)));

// ---------------------------------------------------------------------------
// Kernel 1: Weff -> fragment-ordered bf16 image in ws.
// value at [s][o16][ks][l][e] = 0.25*sum_ns sketches[n][f][s']*sgn[n][s'][o]
//   with o = o16*16 + (l&15), c = (s&1)*64 + ks*32 + (l>>4)*8 + e,
//   f = c*9 + (s>>1).
// grid 144 (=1152/8 f-blocks), block 256 (o = tid).
// ---------------------------------------------------------------------------
#define FPB 8
__global__ __launch_bounds__(256) void weff_kernel(
    const float* __restrict__ sketches,   // (4, 1152, 128)
    const float* __restrict__ sgn,        // (4, 128, 256)
    char* __restrict__ wsA)
{
  __shared__ alignas(16) float sk[512 * FPB];   // [ns][fi], 16 KB
  const int f0 = blockIdx.x * FPB;
  const int t  = threadIdx.x;

  for (int k = 0; k < (512 * FPB) / 256; ++k) {
    int idx = t + k * 256;
    int fi  = idx >> 9;
    int ns  = idx & 511;
    int n   = ns >> 7;
    int s   = ns & 127;
    sk[ns * FPB + fi] = sketches[(n * 1152 + f0 + fi) * 128 + s];
  }
  __syncthreads();

  const int o = t;
  float acc[FPB] = {};
#pragma unroll 4
  for (int ns = 0; ns < 512; ++ns) {
    float sg = sgn[ns * 256 + o];
    const f32x4* skv = (const f32x4*)&sk[ns * FPB];
    f32x4 a = skv[0], b = skv[1];
    acc[0] += sg * a[0]; acc[1] += sg * a[1];
    acc[2] += sg * a[2]; acc[3] += sg * a[3];
    acc[4] += sg * b[0]; acc[5] += sg * b[1];
    acc[6] += sg * b[2]; acc[7] += sg * b[3];
  }

#pragma unroll
  for (int fi = 0; fi < FPB; ++fi) {
    int f    = f0 + fi;
    int c    = f / 9;
    int khkw = f - c * 9;
    int s    = khkw * 2 + (c >> 6);
    int kk   = c & 63;
    int ks   = kk >> 5;
    int ke   = kk & 31;
    int l    = ((ke >> 3) << 4) | (o & 15);
    int e    = ke & 7;
    size_t off = (size_t)s * A_TILE_BYTES
               + (size_t)(((o >> 4) * 2 + ks)) * 1024
               + (size_t)l * 16 + (size_t)e * 2;
    *(__hip_bfloat16*)(wsA + off) = __float2bfloat16(acc[fi] * 0.25f);
  }
}

// ---------------------------------------------------------------------------
// Kernel 2: implicit-GEMM conv, barrier-free K-loop.
// Block (b,i): 256 o x 64 j, 4 waves (wave w owns o in [64w,64w+64)).
// ---------------------------------------------------------------------------
__global__ __launch_bounds__(256, 2) void conv_kernel(
    const float* __restrict__ x,
    const char*  __restrict__ wA,
    const float* __restrict__ bias,
    float* __restrict__ out)
{
  __shared__ alignas(16) char ldsB[49152];   // [3][64 j][128 c] bf16, swizzled

  const int bid = blockIdx.x;
  const int swz = (bid & 7) * 248 + (bid >> 3);   // 1984 = 8*248, bijective
  const int b   = swz / H2;
  const int i   = swz - b * H2;

  const int t    = threadIdx.x;
  const int lane = t & 63;
  const int w    = t >> 6;

  // ---- stage B once: x[b, :, i..i+2, :] -> bf16 LDS [r][j][c], swizzled
  {
    const int j  = t & 63;
    const int cq = t >> 6;                         // 4 groups of 32 channels
    const uint32_t swb = (uint32_t)((j & 7) << 4);
#pragma unroll
    for (int r = 0; r < 3; ++r) {
      const float* xr = x + (((size_t)(b * CIN + cq * 32)) * HH + (i + r)) * WW + j;
      char* lrow = ldsB + (r * 64 + j) * 256;
#pragma unroll
      for (int g = 0; g < 4; ++g) {
        bf16x8 pk;
#pragma unroll
        for (int cc = 0; cc < 8; ++cc)
          pk[cc] = (__bf16)xr[(size_t)(g * 8 + cc) * (HH * WW)];
        uint32_t c0b = (uint32_t)(cq * 64 + g * 16);
        *(bf16x8*)(lrow + (c0b ^ swb)) = pk;
      }
    }
  }

  // ---- prologue: A fragments for step 0 into registers
  bf16x8 ab[2][8];                                 // [s&1][mi*2+ks]
  const char* aw = wA + (w * 8) * 1024 + lane * 16;
#pragma unroll
  for (int q = 0; q < 8; ++q)
    ab[0][q] = *(const bf16x8*)(aw + q * 1024);

  __syncthreads();                                 // B tile ready (only barrier)

  f32x4 acc[4][4];
  const f32x4 zf = {0.f, 0.f, 0.f, 0.f};
#pragma unroll
  for (int mi = 0; mi < 4; ++mi)
#pragma unroll
    for (int ni = 0; ni < 4; ++ni)
      acc[mi][ni] = zf;

  const int ln15 = lane & 15;
  const int khi16 = (lane >> 4) * 16;              // byte offset of 8-elem k-group

#pragma unroll
  for (int s = 0; s < NSTEP; ++s) {
    // prefetch A for step s+1 (registers, 1 KB per fragment, L2-resident)
    if (s < NSTEP - 1) {
      const char* an = aw + (s + 1) * A_TILE_BYTES;
#pragma unroll
      for (int q = 0; q < 8; ++q)
        ab[(s + 1) & 1][q] = *(const bf16x8*)(an + q * 1024);
    }

    const int khkw = s >> 1;                       // compile-time after unroll
    const int kh   = khkw / 3;
    const int kw   = khkw - kh * 3;
    const int chb  = (s & 1) * 128;                // byte offset of c-half

    bf16x8 bfr[4][2];
#pragma unroll
    for (int ni = 0; ni < 4; ++ni) {
      int colr = ni * 16 + ln15 + kw;
      int col  = colr > 63 ? 63 : colr;            // pads only j>=62 (discarded)
      const char* brow = ldsB + (kh * 64 + col) * 256;
      uint32_t sw = (uint32_t)((col & 7) << 4);
#pragma unroll
      for (int ks = 0; ks < 2; ++ks) {
        uint32_t cb = (uint32_t)(chb + ks * 64 + khi16);
        bfr[ni][ks] = *(const bf16x8*)(brow + (cb ^ sw));
      }
    }

#pragma unroll
    for (int mi = 0; mi < 4; ++mi)
#pragma unroll
      for (int ni = 0; ni < 4; ++ni) {
        acc[mi][ni] = __builtin_amdgcn_mfma_f32_16x16x32_bf16(
            ab[s & 1][mi * 2 + 0], bfr[ni][0], acc[mi][ni], 0, 0, 0);
        acc[mi][ni] = __builtin_amdgcn_mfma_f32_16x16x32_bf16(
            ab[s & 1][mi * 2 + 1], bfr[ni][1], acc[mi][ni], 0, 0, 0);
      }
  }

  // ---- epilogue: D[m][n]: m=(lane>>4)*4+reg, n=lane&15
  const int jn = lane & 15;
  const int g4 = lane >> 4;
#pragma unroll
  for (int mi = 0; mi < 4; ++mi) {
#pragma unroll
    for (int ni = 0; ni < 4; ++ni) {
      const int jj = (ni << 4) + jn;
      if (jj < W2) {
#pragma unroll
        for (int rr = 0; rr < 4; ++rr) {
          const int o = (w << 6) + (mi << 4) + (g4 << 2) + rr;
          out[(((size_t)b * OUTC + o) * H2 + i) * W2 + jj] = acc[mi][ni][rr] + bias[o];
        }
      }
    }
  }
}

extern "C" void kernel_launch(void* const* d_in, const int* in_sizes, int n_in,
                              void* d_out, int out_size, void* d_ws, size_t ws_size,
                              hipStream_t stream) {
  const float* x        = (const float*)d_in[0];
  const float* sketches = (const float*)d_in[1];
  const float* sgn      = (const float*)d_in[2];
  const float* bias     = (const float*)d_in[3];
  float* out            = (float*)d_out;
  char* wsA             = (char*)d_ws;

  if (ws_size < (size_t)WS_A_BYTES) return;  // need 576 KB scratch

  weff_kernel<<<1152 / FPB, 256, 0, stream>>>(sketches, sgn, wsA);
  conv_kernel<<<BATCH * H2, 256, 0, stream>>>(x, wsA, bias, out);
}

// Round 3
// 138.574 us; speedup vs baseline: 1.0737x; 1.0737x over previous
//
#include <hip/hip_runtime.h>
#include <hip/hip_bf16.h>
#include <stdint.h>

// SketchConv2d: out = conv2d(x, Weff) + bias, where
// Weff[o,f] = (1/4) * sum_{n,s} sketches[n,f,s] * signed[n,s,o]
// f channel-major flat (c*9 + kh*3 + kw).
//
// B=32, CIN=128, H=W=64, OUT=256, KH=KW=3, H2=W2=62, NSK=4, SDIM=128.
//
// Round 3: round-2 structure with STATIC register discipline.
//  - all 18 K-steps macro-expanded; A double-buffer = named A0/A1 arrays
//    with literal indices only (fixes rule-#20 scratch demotion that kept
//    round 2 at 142 us with VGPR_Count=84).
//  - B LDS tile padded to [3][68 rows][256 B] so no clamp needed; ds_reads
//    become 6 precomputed base VGPRs + 16-bit immediates.

#define BATCH 32
#define CIN   128
#define HH    64
#define WW    64
#define OUTC  256
#define H2    62
#define W2    62
#define A_TILE_BYTES 32768            // per step: 16 o16 * 2 ks * 1024
#define WS_A_BYTES (18 * A_TILE_BYTES)
#define BROW 17408                    // 68 rows * 256 B per kh block

typedef __bf16 bf16x8 __attribute__((ext_vector_type(8)));
typedef float  f32x4  __attribute__((ext_vector_type(4)));

// ---------------------------------------------------------------------------
// Kernel 1: Weff -> fragment-ordered bf16 image in ws (unchanged from r2).
// [step s(18)][o16(16)][ks(2)][lane(64)][8 bf16]
// ---------------------------------------------------------------------------
#define FPB 8
__global__ __launch_bounds__(256) void weff_kernel(
    const float* __restrict__ sketches,   // (4, 1152, 128)
    const float* __restrict__ sgn,        // (4, 128, 256)
    char* __restrict__ wsA)
{
  __shared__ alignas(16) float sk[512 * FPB];
  const int f0 = blockIdx.x * FPB;
  const int t  = threadIdx.x;

  for (int k = 0; k < (512 * FPB) / 256; ++k) {
    int idx = t + k * 256;
    int fi  = idx >> 9;
    int ns  = idx & 511;
    int n   = ns >> 7;
    int s   = ns & 127;
    sk[ns * FPB + fi] = sketches[(n * 1152 + f0 + fi) * 128 + s];
  }
  __syncthreads();

  const int o = t;
  float acc[FPB] = {};
#pragma unroll 4
  for (int ns = 0; ns < 512; ++ns) {
    float sg = sgn[ns * 256 + o];
    const f32x4* skv = (const f32x4*)&sk[ns * FPB];
    f32x4 a = skv[0], b = skv[1];
    acc[0] += sg * a[0]; acc[1] += sg * a[1];
    acc[2] += sg * a[2]; acc[3] += sg * a[3];
    acc[4] += sg * b[0]; acc[5] += sg * b[1];
    acc[6] += sg * b[2]; acc[7] += sg * b[3];
  }

#pragma unroll
  for (int fi = 0; fi < FPB; ++fi) {
    int f    = f0 + fi;
    int c    = f / 9;
    int khkw = f - c * 9;
    int s    = khkw * 2 + (c >> 6);
    int kk   = c & 63;
    int ks   = kk >> 5;
    int ke   = kk & 31;
    int l    = ((ke >> 3) << 4) | (o & 15);
    int e    = ke & 7;
    size_t off = (size_t)s * A_TILE_BYTES
               + (size_t)(((o >> 4) * 2 + ks)) * 1024
               + (size_t)l * 16 + (size_t)e * 2;
    *(__hip_bfloat16*)(wsA + off) = __float2bfloat16(acc[fi] * 0.25f);
  }
}

// ---------------------------------------------------------------------------
// Kernel 2: implicit-GEMM conv, fully unrolled K-loop, static registers.
// Block (b,i): 256 o x 64 j, 4 waves (wave w owns o in [64w,64w+64)).
// ---------------------------------------------------------------------------
__global__ __launch_bounds__(256, 3) void conv_kernel(
    const float* __restrict__ x,
    const char*  __restrict__ wA,
    const float* __restrict__ bias,
    float* __restrict__ out)
{
  __shared__ alignas(16) char ldsB[3 * BROW];   // [kh][68 j][128 c] bf16, swz

  const int bid = blockIdx.x;
  const int swz = (bid & 7) * 248 + (bid >> 3);   // 1984 = 8*248, bijective
  const int b   = swz / H2;
  const int i   = swz - b * H2;

  const int t    = threadIdx.x;
  const int lane = t & 63;
  const int w    = t >> 6;

  // ---- stage B once: x[b, :, i..i+2, :] -> bf16 LDS [kh][j][c], swizzled
  {
    const int j  = t & 63;
    const int cq = t >> 6;
    const uint32_t swb = (uint32_t)((j & 7) << 4);
#pragma unroll
    for (int r = 0; r < 3; ++r) {
      const float* xr = x + (((size_t)(b * CIN + cq * 32)) * HH + (i + r)) * WW + j;
      char* lrow = ldsB + r * BROW + j * 256;
#pragma unroll
      for (int g = 0; g < 4; ++g) {
        bf16x8 pk;
#pragma unroll
        for (int cc = 0; cc < 8; ++cc)
          pk[cc] = (__bf16)xr[(size_t)(g * 8 + cc) * (HH * WW)];
        uint32_t c0b = (uint32_t)(cq * 64 + g * 16);
        *(bf16x8*)(lrow + (c0b ^ swb)) = pk;
      }
    }
  }

  // ---- precomputed B read bases: pB<kw><ks>, all ds_reads use +imm
  const int ln15  = lane & 15;
  const int khi16 = (lane >> 4) << 4;
#define MKB(KW, KS) (ldsB + (ln15 + (KW)) * 256 \
                     + (((uint32_t)(((KS) << 6) | khi16)) ^ ((uint32_t)(((ln15 + (KW)) & 7) << 4))))
  const char* pB00 = MKB(0, 0); const char* pB01 = MKB(0, 1);
  const char* pB10 = MKB(1, 0); const char* pB11 = MKB(1, 1);
  const char* pB20 = MKB(2, 0); const char* pB21 = MKB(2, 1);
#undef MKB

  // ---- A fragment base for this wave
  const char* aw = wA + (w * 8) * 1024 + lane * 16;

  bf16x8 A0[8], A1[8];

#define PF(AN, S) do { const char* an_ = aw + (S) * A_TILE_BYTES;          \
    AN[0] = *(const bf16x8*)(an_);         AN[1] = *(const bf16x8*)(an_ + 1024); \
    AN[2] = *(const bf16x8*)(an_ + 2048);  AN[3] = *(const bf16x8*)(an_ + 3072); \
    AN[4] = *(const bf16x8*)(an_ + 4096);  AN[5] = *(const bf16x8*)(an_ + 5120); \
    AN[6] = *(const bf16x8*)(an_ + 6144);  AN[7] = *(const bf16x8*)(an_ + 7168); \
  } while (0)

  PF(A0, 0);             // step-0 A fragments

  f32x4 acc[4][4];
  const f32x4 zf = {0.f, 0.f, 0.f, 0.f};
#pragma unroll
  for (int mi = 0; mi < 4; ++mi)
#pragma unroll
    for (int ni = 0; ni < 4; ++ni)
      acc[mi][ni] = zf;

  __syncthreads();       // B tile ready (only barrier)

#define MFMA_ __builtin_amdgcn_mfma_f32_16x16x32_bf16

#define KSBLK(AC, PB, IMM, KS) do {                                        \
    bf16x8 b0_ = *(const bf16x8*)((PB) + (IMM));                           \
    bf16x8 b1_ = *(const bf16x8*)((PB) + (IMM) + 4096);                    \
    bf16x8 b2_ = *(const bf16x8*)((PB) + (IMM) + 8192);                    \
    bf16x8 b3_ = *(const bf16x8*)((PB) + (IMM) + 12288);                   \
    acc[0][0] = MFMA_(AC[0*2+(KS)], b0_, acc[0][0], 0, 0, 0);              \
    acc[0][1] = MFMA_(AC[0*2+(KS)], b1_, acc[0][1], 0, 0, 0);              \
    acc[0][2] = MFMA_(AC[0*2+(KS)], b2_, acc[0][2], 0, 0, 0);              \
    acc[0][3] = MFMA_(AC[0*2+(KS)], b3_, acc[0][3], 0, 0, 0);              \
    acc[1][0] = MFMA_(AC[1*2+(KS)], b0_, acc[1][0], 0, 0, 0);              \
    acc[1][1] = MFMA_(AC[1*2+(KS)], b1_, acc[1][1], 0, 0, 0);              \
    acc[1][2] = MFMA_(AC[1*2+(KS)], b2_, acc[1][2], 0, 0, 0);              \
    acc[1][3] = MFMA_(AC[1*2+(KS)], b3_, acc[1][3], 0, 0, 0);              \
    acc[2][0] = MFMA_(AC[2*2+(KS)], b0_, acc[2][0], 0, 0, 0);              \
    acc[2][1] = MFMA_(AC[2*2+(KS)], b1_, acc[2][1], 0, 0, 0);              \
    acc[2][2] = MFMA_(AC[2*2+(KS)], b2_, acc[2][2], 0, 0, 0);              \
    acc[2][3] = MFMA_(AC[2*2+(KS)], b3_, acc[2][3], 0, 0, 0);              \
    acc[3][0] = MFMA_(AC[3*2+(KS)], b0_, acc[3][0], 0, 0, 0);              \
    acc[3][1] = MFMA_(AC[3*2+(KS)], b1_, acc[3][1], 0, 0, 0);              \
    acc[3][2] = MFMA_(AC[3*2+(KS)], b2_, acc[3][2], 0, 0, 0);              \
    acc[3][3] = MFMA_(AC[3*2+(KS)], b3_, acc[3][3], 0, 0, 0);              \
  } while (0)

  // one K-step (BK=64): 8 ds_read_b128 + 32 MFMA. imm <= 2*17408+12288+128
#define STEP(AC, KH, KW, CHB) do {                                         \
    KSBLK(AC, pB##KW##0, (KH) * BROW + (CHB), 0);                          \
    KSBLK(AC, pB##KW##1, (KH) * BROW + (CHB), 1);                          \
  } while (0)

#define TAP(T, KH, KW) do {                                                \
    PF(A1, 2 * (T) + 1);                                                   \
    STEP(A0, KH, KW, 0);                                                   \
    PF(A0, 2 * (T) + 2);                                                   \
    STEP(A1, KH, KW, 128);                                                 \
  } while (0)

#define TAP_LAST(T, KH, KW) do {                                           \
    PF(A1, 2 * (T) + 1);                                                   \
    STEP(A0, KH, KW, 0);                                                   \
    STEP(A1, KH, KW, 128);                                                 \
  } while (0)

  TAP(0, 0, 0);  TAP(1, 0, 1);  TAP(2, 0, 2);
  TAP(3, 1, 0);  TAP(4, 1, 1);  TAP(5, 1, 2);
  TAP(6, 2, 0);  TAP(7, 2, 1);  TAP_LAST(8, 2, 2);

#undef TAP_LAST
#undef TAP
#undef STEP
#undef KSBLK
#undef MFMA_
#undef PF

  // ---- epilogue: D[m][n]: m=(lane>>4)*4+reg, n=lane&15
  const int jn = lane & 15;
  const int g4 = lane >> 4;
#pragma unroll
  for (int mi = 0; mi < 4; ++mi) {
#pragma unroll
    for (int ni = 0; ni < 4; ++ni) {
      const int jj = (ni << 4) + jn;
      if (jj < W2) {
#pragma unroll
        for (int rr = 0; rr < 4; ++rr) {
          const int o = (w << 6) + (mi << 4) + (g4 << 2) + rr;
          out[(((size_t)b * OUTC + o) * H2 + i) * W2 + jj] = acc[mi][ni][rr] + bias[o];
        }
      }
    }
  }
}

extern "C" void kernel_launch(void* const* d_in, const int* in_sizes, int n_in,
                              void* d_out, int out_size, void* d_ws, size_t ws_size,
                              hipStream_t stream) {
  const float* x        = (const float*)d_in[0];
  const float* sketches = (const float*)d_in[1];
  const float* sgn      = (const float*)d_in[2];
  const float* bias     = (const float*)d_in[3];
  float* out            = (float*)d_out;
  char* wsA             = (char*)d_ws;

  if (ws_size < (size_t)WS_A_BYTES) return;  // need 576 KB scratch

  weff_kernel<<<1152 / FPB, 256, 0, stream>>>(sketches, sgn, wsA);
  conv_kernel<<<BATCH * H2, 256, 0, stream>>>(x, wsA, bias, out);
}

// Round 4
// 115.390 us; speedup vs baseline: 1.2894x; 1.2009x over previous
//
#include <hip/hip_runtime.h>
#include <hip/hip_bf16.h>
#include <stdint.h>

// SketchConv2d: out = conv2d(x, Weff) + bias, where
// Weff[o,f] = (1/4) * sum_{n,s} sketches[n,f,s] * signed[n,s,o]
// f channel-major flat (c*9 + kh*3 + kw).
//
// B=32, CIN=128, H=W=64, OUT=256, KH=KW=3, H2=W2=62, NSK=4, SDIM=128.
//
// Round 4: T3-min pipeline (guide §5.5).
//  - A (Weff) staged per K-step via global_load_lds into a DOUBLE-BUFFERED
//    32 KB LDS tile (pre-swizzled image in ws); stage(s+1) issued before
//    compute(s) -> latency hidden; one __syncthreads per step.
//  - B (x rows) staged ONCE per block: 4 rows, [4][68 j][256 B] bf16 swz.
//  - block = 512 thr / 8 waves = 256 o x 64 j x 2 i-rows;
//    wave (w>>1)=o-quarter, (w&1)=i-row. Halves A L2 traffic vs 1-row.

#define BATCH 32
#define CIN   128
#define HH    64
#define WW    64
#define OUTC  256
#define H2    62
#define W2    62
#define A_TILE 32768                  // 256 o x 64 k x 2B per step
#define WS_A_BYTES (18 * A_TILE)
#define BKHB  17408                   // 68 j-rows * 256 B per x-row

typedef __bf16 bf16x8 __attribute__((ext_vector_type(8)));
typedef float  f32x4  __attribute__((ext_vector_type(4)));

typedef unsigned int u32_as1 __attribute__((address_space(1)));
typedef unsigned int u32_as3 __attribute__((address_space(3)));

__device__ __forceinline__ void async_copy16(const void* g, void* l) {
  __builtin_amdgcn_global_load_lds((const u32_as1*)g, (u32_as3*)l, 16, 0, 0);
}

// ---------------------------------------------------------------------------
// Kernel 1: Weff -> 18 pre-swizzled LDS tile images in ws.
// image byte: s*32768 + o*128 + ((kk*2) ^ ((o&7)<<4)),  kk = c & 63,
// s = (kh*3+kw)*2 + (c>>6).
// ---------------------------------------------------------------------------
#define FPB 4
__global__ __launch_bounds__(256) void weff_kernel(
    const float* __restrict__ sketches,   // (4, 1152, 128)
    const float* __restrict__ sgn,        // (4, 128, 256)
    char* __restrict__ wsA)
{
  __shared__ alignas(16) float sk[512 * FPB];
  const int f0 = blockIdx.x * FPB;
  const int t  = threadIdx.x;

  for (int k = 0; k < (512 * FPB) / 256; ++k) {
    int idx = t + k * 256;
    int fi  = idx >> 9;
    int ns  = idx & 511;
    int n   = ns >> 7;
    int s   = ns & 127;
    sk[ns * FPB + fi] = sketches[(n * 1152 + f0 + fi) * 128 + s];
  }
  __syncthreads();

  const int o = t;
  float acc0 = 0.f, acc1 = 0.f, acc2 = 0.f, acc3 = 0.f;
#pragma unroll 8
  for (int ns = 0; ns < 512; ++ns) {
    float sg = sgn[ns * 256 + o];
    f32x4 skv = *(const f32x4*)(&sk[ns * FPB]);
    acc0 += sg * skv[0];
    acc1 += sg * skv[1];
    acc2 += sg * skv[2];
    acc3 += sg * skv[3];
  }

  float accs[FPB] = {acc0, acc1, acc2, acc3};
#pragma unroll
  for (int fi = 0; fi < FPB; ++fi) {
    int f    = f0 + fi;
    int c    = f / 9;
    int khkw = f - c * 9;
    int s    = khkw * 2 + (c >> 6);
    int kk   = c & 63;
    uint32_t byteoff = (uint32_t)s * A_TILE + (uint32_t)o * 128
                     + (((uint32_t)kk * 2u) ^ (uint32_t)((o & 7) << 4));
    *(__hip_bfloat16*)(wsA + byteoff) = __float2bfloat16(accs[fi] * 0.25f);
  }
}

// ---------------------------------------------------------------------------
// Kernel 2: implicit-GEMM conv, A-dbuf via global_load_lds, B LDS-resident.
// ---------------------------------------------------------------------------
__global__ __launch_bounds__(512, 2) void conv_kernel(
    const float* __restrict__ x,
    const char*  __restrict__ wA,
    const float* __restrict__ bias,
    float* __restrict__ out)
{
  __shared__ alignas(16) char lds[65536 + 4 * BKHB];   // 64 KB A-dbuf + 68 KB B
  char* ldsA = lds;
  char* ldsB = lds + 65536;

  const int bid = blockIdx.x;
  const int swz = (bid & 7) * 124 + (bid >> 3);   // 992 = 8*124, bijective
  const int b   = swz / 31;
  const int ip  = swz - b * 31;
  const int i0  = ip * 2;

  const int t    = threadIdx.x;
  const int lane = t & 63;
  const int w    = t >> 6;       // 0..7
  const int wo   = w >> 1;       // o-quarter
  const int ir   = w & 1;        // i-row of the pair

  // ---- stage A step 0 into buf 0 (overlaps with B staging below)
#define STAGE_A(LIN, BUF) do {                                             \
    const char* asrc_ = wA + (size_t)(LIN) * A_TILE + w * 1024 + lane * 16;\
    char* adst_ = ldsA + (BUF) * 32768 + w * 1024;                         \
    async_copy16(asrc_,          adst_);                                   \
    async_copy16(asrc_ + 8192,   adst_ + 8192);                            \
    async_copy16(asrc_ + 16384,  adst_ + 16384);                           \
    async_copy16(asrc_ + 24576,  adst_ + 24576);                           \
  } while (0)

  STAGE_A(0, 0);

  // ---- stage B once: x[b, :, i0..i0+3, :] -> bf16 LDS [r][j][c], swizzled
  {
    const int j  = t & 63;
    const int cq = t >> 6;                         // 8 groups of 16 channels
    const uint32_t swb = (uint32_t)((j & 7) << 4);
#pragma unroll
    for (int r = 0; r < 4; ++r) {
      const float* xr = x + (((size_t)(b * CIN + cq * 16)) * HH + (i0 + r)) * WW + j;
      char* lrow = ldsB + r * BKHB + j * 256;
#pragma unroll
      for (int g = 0; g < 2; ++g) {
        bf16x8 pk;
#pragma unroll
        for (int cc = 0; cc < 8; ++cc)
          pk[cc] = (__bf16)xr[(size_t)(g * 8 + cc) * (HH * WW)];
        uint32_t c0b = (uint32_t)(cq * 32 + g * 16);
        *(bf16x8*)(lrow + (c0b ^ swb)) = pk;
      }
    }
    // zero the 4 pad j-rows (64..67) of each x-row
    if (t < 256) {
      int r  = t >> 6;
      int pj = 64 + ((t >> 4) & 3);
      int sl = (t & 15) * 16;
      bf16x8 z = {};
      *(bf16x8*)(ldsB + r * BKHB + pj * 256 + sl) = z;
    }
  }

  f32x4 acc[4][4];
  const f32x4 zf = {0.f, 0.f, 0.f, 0.f};
#pragma unroll
  for (int mi = 0; mi < 4; ++mi)
#pragma unroll
    for (int ni = 0; ni < 4; ++ni)
      acc[mi][ni] = zf;

  __syncthreads();   // drains stage(0) + B writes

  // ---- per-lane LDS read bases
  const int ln15  = lane & 15;
  const int khi16 = (lane >> 4) << 4;
  const uint32_t swa = (uint32_t)((ln15 & 7) << 4);
  const char* pAr = ldsA + (wo * 64 + ln15) * 128;
  const char* pA0 = pAr + (((uint32_t)khi16) ^ swa);          // ks=0
  const char* pA1 = pAr + (((uint32_t)(64 | khi16)) ^ swa);   // ks=1

#define MKB(KW, KS) (ldsB + ir * BKHB + (ln15 + (KW)) * 256                \
    + (((uint32_t)(((KS) << 6) | khi16)) ^ ((uint32_t)(((ln15 + (KW)) & 7) << 4))))
  const char* pB00 = MKB(0, 0); const char* pB01 = MKB(0, 1);
  const char* pB10 = MKB(1, 0); const char* pB11 = MKB(1, 1);
  const char* pB20 = MKB(2, 0); const char* pB21 = MKB(2, 1);
#undef MKB

#define MFMA_ __builtin_amdgcn_mfma_f32_16x16x32_bf16

#define KSBLK(LIN, KH, KW, KS) do {                                        \
    const int ai_ = ((LIN) & 1) * 32768;                                   \
    bf16x8 a0_ = *(const bf16x8*)(pA##KS + ai_);                           \
    bf16x8 a1_ = *(const bf16x8*)(pA##KS + ai_ + 2048);                    \
    bf16x8 a2_ = *(const bf16x8*)(pA##KS + ai_ + 4096);                    \
    bf16x8 a3_ = *(const bf16x8*)(pA##KS + ai_ + 6144);                    \
    const int bi_ = (KH) * BKHB + ((LIN) & 1) * 128;                       \
    bf16x8 b0_ = *(const bf16x8*)(pB##KW##KS + bi_);                       \
    bf16x8 b1_ = *(const bf16x8*)(pB##KW##KS + bi_ + 4096);                \
    bf16x8 b2_ = *(const bf16x8*)(pB##KW##KS + bi_ + 8192);                \
    bf16x8 b3_ = *(const bf16x8*)(pB##KW##KS + bi_ + 12288);               \
    acc[0][0] = MFMA_(a0_, b0_, acc[0][0], 0, 0, 0);                       \
    acc[0][1] = MFMA_(a0_, b1_, acc[0][1], 0, 0, 0);                       \
    acc[0][2] = MFMA_(a0_, b2_, acc[0][2], 0, 0, 0);                       \
    acc[0][3] = MFMA_(a0_, b3_, acc[0][3], 0, 0, 0);                       \
    acc[1][0] = MFMA_(a1_, b0_, acc[1][0], 0, 0, 0);                       \
    acc[1][1] = MFMA_(a1_, b1_, acc[1][1], 0, 0, 0);                       \
    acc[1][2] = MFMA_(a1_, b2_, acc[1][2], 0, 0, 0);                       \
    acc[1][3] = MFMA_(a1_, b3_, acc[1][3], 0, 0, 0);                       \
    acc[2][0] = MFMA_(a2_, b0_, acc[2][0], 0, 0, 0);                       \
    acc[2][1] = MFMA_(a2_, b1_, acc[2][1], 0, 0, 0);                       \
    acc[2][2] = MFMA_(a2_, b2_, acc[2][2], 0, 0, 0);                       \
    acc[2][3] = MFMA_(a2_, b3_, acc[2][3], 0, 0, 0);                       \
    acc[3][0] = MFMA_(a3_, b0_, acc[3][0], 0, 0, 0);                       \
    acc[3][1] = MFMA_(a3_, b1_, acc[3][1], 0, 0, 0);                       \
    acc[3][2] = MFMA_(a3_, b2_, acc[3][2], 0, 0, 0);                       \
    acc[3][3] = MFMA_(a3_, b3_, acc[3][3], 0, 0, 0);                       \
  } while (0)

  // one K-step: issue next stage, compute current from LDS, barrier.
#define STEP(LIN, KH, KW) do {                                             \
    if ((LIN) < 17) STAGE_A((LIN) + 1, ((LIN) + 1) & 1);                   \
    KSBLK(LIN, KH, KW, 0);                                                 \
    KSBLK(LIN, KH, KW, 1);                                                 \
    __syncthreads();                                                       \
  } while (0)

  STEP(0, 0, 0);   STEP(1, 0, 0);
  STEP(2, 0, 1);   STEP(3, 0, 1);
  STEP(4, 0, 2);   STEP(5, 0, 2);
  STEP(6, 1, 0);   STEP(7, 1, 0);
  STEP(8, 1, 1);   STEP(9, 1, 1);
  STEP(10, 1, 2);  STEP(11, 1, 2);
  STEP(12, 2, 0);  STEP(13, 2, 0);
  STEP(14, 2, 1);  STEP(15, 2, 1);
  STEP(16, 2, 2);  STEP(17, 2, 2);

#undef STEP
#undef KSBLK
#undef MFMA_
#undef STAGE_A

  // ---- epilogue: D[m][n]: m=(lane>>4)*4+reg, n=lane&15
  const int jn   = ln15;
  const int g4   = lane >> 4;
  const int irow = i0 + ir;
#pragma unroll
  for (int mi = 0; mi < 4; ++mi) {
#pragma unroll
    for (int ni = 0; ni < 4; ++ni) {
      const int jj = (ni << 4) + jn;
      if (jj < W2) {
#pragma unroll
        for (int rr = 0; rr < 4; ++rr) {
          const int o = (wo << 6) + (mi << 4) + (g4 << 2) + rr;
          out[(((size_t)b * OUTC + o) * H2 + irow) * W2 + jj] = acc[mi][ni][rr] + bias[o];
        }
      }
    }
  }
}

extern "C" void kernel_launch(void* const* d_in, const int* in_sizes, int n_in,
                              void* d_out, int out_size, void* d_ws, size_t ws_size,
                              hipStream_t stream) {
  const float* x        = (const float*)d_in[0];
  const float* sketches = (const float*)d_in[1];
  const float* sgn      = (const float*)d_in[2];
  const float* bias     = (const float*)d_in[3];
  float* out            = (float*)d_out;
  char* wsA             = (char*)d_ws;

  if (ws_size < (size_t)WS_A_BYTES) return;  // need 576 KB scratch

  weff_kernel<<<1152 / FPB, 256, 0, stream>>>(sketches, sgn, wsA);
  conv_kernel<<<BATCH * (H2 / 2), 512, 0, stream>>>(x, wsA, bias, out);
}